// Round 5
// baseline (1258.816 us; speedup 1.0000x reference)
//
#include <hip/hip_runtime.h>

// LSTM-like scan. x:[B,T] f32, W:[H+1,H] f32, b:[H] f32 -> out:[B,T,H] f32.
// B=256, T=2048, H=128.
// g_j = sum_i h_i*W[i,j] + x_t*W[H,j] + b_j ; sg = sigmoid(g);
// c = sg*(c+g); h = sg*c; out[b,t,:] = h.
//
// ROUND 5: round-4 structure (passed, 1113us) + the DIRECT allocator knob.
// Round-4 counters showed VGPR_Count=28 < the 32 needed for W alone: the
// allocator evicts W (AGPR moves / scratch) no matter what the source says,
// costing ~700 cyc/step of the measured 1300. We run exactly one 512-thread
// block per CU = 2 waves/SIMD, so amdgpu_waves_per_eu(2,2) grants a
// 256-VGPR/wave budget and removes any occupancy motive to spill.
// Expect VGPR_Count ~56-72 as proof; dur ~550-700us.
//
// Structure recap: 8 waves; wave w: K-chunk q=w>>1 (rows 32q..32q+31),
// partial column j=(w&1)*64+lane. Lane carries c/h state for column
// jj=32q+(lane&31) in REGISTERS; h broadcasts via v_readlane (no LDS h
// buffer). Per step: 32 RL + 32 FMA -> partial -> pb[t&1] -> lgkmcnt(0) +
// s_barrier -> each lane sums 4 partials for jj -> sigmoid/c/h in-register
// -> designated half-waves store out (fire-and-forget, never drained).

#define BB 256
#define TT 2048
#define HH 128
#define NT 512   // 8 waves

#define LOADW(k) \
    float4 w##k = make_float4(W[(kbase + 4*(k)+0)*HH + j], W[(kbase + 4*(k)+1)*HH + j], \
                              W[(kbase + 4*(k)+2)*HH + j], W[(kbase + 4*(k)+3)*HH + j]);

// Make W values asm-defined so they cannot be rematerialized by reloading.
#define KEEPW(k) \
    asm volatile("" : "+v"(w##k.x), "+v"(w##k.y), "+v"(w##k.z), "+v"(w##k.w));

// Broadcast h[kbase+i] from lane i of vh (lanes 0..31 hold the chunk).
#define RL(i) __uint_as_float(__builtin_amdgcn_readlane(__float_as_uint(vh), (i)))

#define MAC4(k) { \
    a0 = fmaf(RL(4*(k)+0), w##k.x, a0); \
    a1 = fmaf(RL(4*(k)+1), w##k.y, a1); \
    a2 = fmaf(RL(4*(k)+2), w##k.z, a2); \
    a3 = fmaf(RL(4*(k)+3), w##k.w, a3); }

__global__ __launch_bounds__(NT)
__attribute__((amdgpu_waves_per_eu(2, 2)))
void lstm_scan_kernel(
    const float* __restrict__ x,   // [B, T]
    const float* __restrict__ W,   // [H+1, H]
    const float* __restrict__ b,   // [H]
    float* __restrict__ out)       // [B, T, H]
{
    const int tid   = threadIdx.x;
    const int lane  = tid & 63;
    const int wave  = tid >> 6;
    const int q     = wave >> 1;                // 0..3 : K chunk
    const int j     = ((wave & 1) << 6) | lane; // 0..127 : partial column
    const int kbase = q << 5;                   // first row of this chunk
    const int jj    = kbase + (lane & 31);      // per-lane state column
    const int batch = blockIdx.x;

    __shared__ float xs[TT];               // 8 KB : this batch row's x
    __shared__ float pb_raw[2 * 4 * HH];   // 4 KB : double-buffered partials
    volatile float* pb = pb_raw;

    for (int t = tid; t < TT; t += NT) {
        xs[t] = x[(size_t)batch * TT + t];
    }

    // W rows [32q, 32q+32) of column j -> 8 named float4s (32 VGPRs).
    LOADW(0) LOADW(1) LOADW(2) LOADW(3) LOADW(4) LOADW(5) LOADW(6) LOADW(7)
    KEEPW(0) KEEPW(1) KEEPW(2) KEEPW(3) KEEPW(4) KEEPW(5) KEEPW(6) KEEPW(7)

    // x-term + bias folded into exactly one K-chunk (q==0).
    const float wx   = (q == 0) ? W[HH * HH + j] : 0.0f;
    const float bias = (q == 0) ? b[j]           : 0.0f;

    float vh = 0.0f;   // h[jj]  (duplicated across lane halves)
    float c  = 0.0f;   // c[jj]
    const bool writer = ((wave & 1) == 0) && (lane < 32);
    float* outp = out + (size_t)batch * TT * HH + jj;

    __syncthreads();   // covers x staging

    for (int t = 0; t < TT; ++t) {
        const int buf = (t & 1) << 9;      // *4*HH

        // ---- MAC phase: partial for column j over rows kbase..kbase+31 ----
        float a0 = fmaf(xs[t], wx, bias);
        float a1 = 0.0f, a2 = 0.0f, a3 = 0.0f;
        MAC4(0) MAC4(1) MAC4(2) MAC4(3) MAC4(4) MAC4(5) MAC4(6) MAC4(7)
        const float part = (a0 + a1) + (a2 + a3);

        pb[buf + q * HH + j] = part;       // banks j%32 : conflict-free

        asm volatile("s_waitcnt lgkmcnt(0)" ::: "memory");
        __builtin_amdgcn_s_barrier();

        // ---- reduce + pointwise, redundantly per lane for its jj ----
        // 4 reads, 2-way same-address across lane halves (free broadcast).
        const float g = (pb[buf + jj] + pb[buf + HH + jj])
                      + (pb[buf + 2 * HH + jj] + pb[buf + 3 * HH + jj]);
        // sigmoid; c+g is independent of the exp/rcp chain -> shorter vh path
        const float sg  = 1.0f / (1.0f + __expf(-g));
        const float cpg = c + g;
        c  = sg * cpg;
        vh = sg * c;                       // next step's h[jj], in-register

        if (writer) outp[(size_t)t * HH] = vh;   // fire-and-forget
    }
}

extern "C" void kernel_launch(void* const* d_in, const int* in_sizes, int n_in,
                              void* d_out, int out_size, void* d_ws, size_t ws_size,
                              hipStream_t stream) {
    const float* x = (const float*)d_in[0];
    const float* W = (const float*)d_in[1];
    const float* b = (const float*)d_in[2];
    float* out = (float*)d_out;

    lstm_scan_kernel<<<BB, NT, 0, stream>>>(x, W, b, out);
}

// Round 7
// 980.708 us; speedup vs baseline: 1.2836x; 1.2836x over previous
//
#include <hip/hip_runtime.h>

// LSTM-like scan. x:[B,T] f32, W:[H+1,H] f32, b:[H] f32 -> out:[B,T,H] f32.
// B=256, T=2048, H=128.
// g_j = sum_i h_i*W[i,j] + x_t*W[H,j] + b_j ; sg = sigmoid(g);
// c = sg*(c+g); h = sg*c; out[b,t,:] = h.
//
// ROUND 7 = ROUND 6 RESUBMIT (broker infra failed twice; kernel audited,
// no hang/correctness hazard found). Theory unchanged:
// Round-5 post-mortem killed the W-residency theory (VGPR 28->88, time
// unchanged at 1113us). Measured step = ~1300 cyc = ~680 VALU issue (the
// 32 readlane broadcast + movs) + ~620 LDS/barrier/sigmoid latency.
//
// COLUMN-SPLIT + DPP BUTTERFLY (replaces K-split across waves):
//  wave w owns cols 16w..16w+15; lane l: col jc=16w+(l>>2), K-chunk s=l&3
//  (rows 32s..32s+31, 32 W floats/lane -- proven resident in round 5).
//  - h broadcast: 8x 4-address-broadcast ds_read_b128 from a x4
//    bank-staggered replica array hrep[buf][4][132] (stride 132 => replica s
//    sits at 656s bytes => per-instr banks 4s+4k..4s+4k+3: conflict-free).
//    FMAs take VGPR operands: NO readlane, NO movs.
//  - K-reduce: 2 DPP quad_perm butterfly adds (pure VALU). All 4 lanes of a
//    quad get g, redundantly compute sigmoid/c/h (replicated state is
//    bit-identical), each lane writes h into ITS replica s of the next
//    double buffer: one ds_write_b32, covers all 4 replicas (<=4-way
//    conflict on that single instruction).
//  - ONE barrier/step. Double buffer makes it race-free: step-t reads are
//    lgkmcnt-drained before barrier t; earliest overwrite of that buffer
//    is a step-(t+1) write, after barrier t in every wave.
// VALU/wave/step ~170 -> ~50. Out stores fire-and-forget (never drained).

#define BB 256
#define TT 2048
#define HH 128
#define NT 512   // 8 waves

#define LOADW(k) \
    float4 w##k = make_float4(W[(kbase + 4*(k)+0)*HH + jc], W[(kbase + 4*(k)+1)*HH + jc], \
                              W[(kbase + 4*(k)+2)*HH + jc], W[(kbase + 4*(k)+3)*HH + jc]);

#define KEEPW(k) \
    asm volatile("" : "+v"(w##k.x), "+v"(w##k.y), "+v"(w##k.z), "+v"(w##k.w));

#define MAC4(k) { \
    const float4 hv = hrd[(k)]; \
    a0 = fmaf(hv.x, w##k.x, a0); \
    a1 = fmaf(hv.y, w##k.y, a1); \
    a2 = fmaf(hv.z, w##k.z, a2); \
    a3 = fmaf(hv.w, w##k.w, a3); }

// Butterfly add over the 4 lanes of each quad (K-chunk reduction).
__device__ __forceinline__ float quad_bfly_sum(float v) {
    // quad_perm [1,0,3,2] = 0xB1 : swap within pairs
    int o1 = __builtin_amdgcn_mov_dpp(__float_as_int(v), 0xB1, 0xf, 0xf, true);
    float p = v + __int_as_float(o1);
    // quad_perm [2,3,0,1] = 0x4E : swap pairs
    int o2 = __builtin_amdgcn_mov_dpp(__float_as_int(p), 0x4E, 0xf, 0xf, true);
    return p + __int_as_float(o2);
}

__global__ __launch_bounds__(NT)
__attribute__((amdgpu_waves_per_eu(2, 2)))
void lstm_scan_kernel(
    const float* __restrict__ x,   // [B, T]
    const float* __restrict__ W,   // [H+1, H]
    const float* __restrict__ b,   // [H]
    float* __restrict__ out)       // [B, T, H]
{
    const int tid   = threadIdx.x;
    const int lane  = tid & 63;
    const int wave  = tid >> 6;
    const int s     = lane & 3;                  // K chunk (rows 32s..32s+31)
    const int jc    = (wave << 4) | (lane >> 2); // owned column
    const int kbase = s << 5;
    const int batch = blockIdx.x;

    __shared__ float xs[TT];             // 8 KB : this batch row's x
    __shared__ float hrep[2][4][132];    // 4.2 KB : dbuf x 4 bank-staggered
                                         // replicas of h[128] (stride 132)

    for (int t = tid; t < TT; t += NT) {
        xs[t] = x[(size_t)batch * TT + t];
    }
    for (int i = tid; i < 4 * 132; i += NT) {
        (&hrep[0][0][0])[i] = 0.0f;      // h(0) = 0 in buffer 0
    }

    // W rows [32s, 32s+32) of column jc -> 8 named float4s (32 VGPRs).
    LOADW(0) LOADW(1) LOADW(2) LOADW(3) LOADW(4) LOADW(5) LOADW(6) LOADW(7)
    KEEPW(0) KEEPW(1) KEEPW(2) KEEPW(3) KEEPW(4) KEEPW(5) KEEPW(6) KEEPW(7)

    // x-term + bias folded into exactly one K-chunk (s==0).
    const float wx   = (s == 0) ? W[HH * HH + jc] : 0.0f;
    const float bias = (s == 0) ? b[jc]           : 0.0f;

    float c = 0.0f;                      // c[jc], replicated across the quad
    float* outp = out + (size_t)batch * TT * HH + jc;

    // Read base: replica s, floats [kbase, kbase+32).
    const float4* hrd0 = (const float4*)&hrep[0][s][kbase];
    const float4* hrd1 = (const float4*)&hrep[1][s][kbase];
    // Write: h[jc] into replica s of the NEXT buffer (quad lanes cover all 4).
    float* hw0 = &hrep[0][s][jc];
    float* hw1 = &hrep[1][s][jc];

    __syncthreads();   // covers x staging + h init

    for (int t = 0; t < TT; ++t) {
        const float4* hrd = (t & 1) ? hrd1 : hrd0;

        // ---- MAC: g-partial for column jc over rows kbase..kbase+31 ----
        float a0 = fmaf(xs[t], wx, bias);
        float a1 = 0.0f, a2 = 0.0f, a3 = 0.0f;
        MAC4(0) MAC4(1) MAC4(2) MAC4(3) MAC4(4) MAC4(5) MAC4(6) MAC4(7)

        // ---- in-wave K-reduction: all 4 quad lanes end with g ----
        const float g = quad_bfly_sum((a0 + a1) + (a2 + a3));

        const float sg = 1.0f / (1.0f + __expf(-g));
        c = sg * (c + g);
        const float hn = sg * c;         // next step's h[jc]

        *((t & 1) ? hw0 : hw1) = hn;     // write buffer (t+1)&1, replica s
        if (s == 0) outp[(size_t)t * HH] = hn;   // fire-and-forget

        asm volatile("s_waitcnt lgkmcnt(0)" ::: "memory");
        __builtin_amdgcn_s_barrier();
        asm volatile("" ::: "memory");   // keep next reads below the barrier
    }
}

extern "C" void kernel_launch(void* const* d_in, const int* in_sizes, int n_in,
                              void* d_out, int out_size, void* d_ws, size_t ws_size,
                              hipStream_t stream) {
    const float* x = (const float*)d_in[0];
    const float* W = (const float*)d_in[1];
    const float* b = (const float*)d_in[2];
    float* out = (float*)d_out;

    lstm_scan_kernel<<<BB, NT, 0, stream>>>(x, W, b, out);
}

// Round 8
// 865.325 us; speedup vs baseline: 1.4547x; 1.1333x over previous
//
#include <hip/hip_runtime.h>

// LSTM-like scan. x:[B,T] f32, W:[H+1,H] f32, b:[H] f32 -> out:[B,T,H] f32.
// B=256, T=2048, H=128.
// g_j = sum_i h_i*W[i,j] + x_t*W[H,j] + b_j ; sg = sigmoid(g);
// c = sg*(c+g); h = sg*c; out[b,t,:] = h.
//
// ROUND 8: round-7 counters showed the LDS return bus is the floor:
// 64 b128 reads/step/CU (64KB broadcast traffic) ~= 512+ cyc, + 8.4M bank
// conflicts on the replica writes. Fix: K-split x16 so each lane reads only
// 8 h floats (2 b128); reduction moves into registers via DPP row_ror
// butterflies. LDS traffic/step: 64KB -> 16KB; h write conflict-free.
//
// Layout: 512 thr = 8 waves, 1 block/CU. Lane l of wave w:
//   s = l&15 : K-chunk rows [8s, 8s+8)   (DPP row position)
//   m = l>>4 : col subgroup; cols c0..c0+3, c0 = 16w + 4m
//   W/lane = 8 rows x 4 cols = 32 floats (8 float4, proven resident r5-r7).
// Per step: 2x b128 h-read (stride-12 staggered groups: banks 12s%32 =>
// exactly 2-way aliasing = free) + 1 b32 xs read -> 32 FMA into 4 col
// accumulators -> 4x4 row_ror DPP butterfly adds (all 16 row lanes get all
// 4 col sums) -> 3 cndmask pick own col (q=s&3) -> g = fma(xt,wx, sum+b)
// -> sigmoid/c/h in-register (state replicated x4, bit-identical) ->
// lanes s<4 write h to LDS (conflict-free) + out (fire-and-forget).
// ONE barrier/step; h double-buffered (race-free: iter-t reads drained
// before barrier t; earliest conflicting write is after barrier t).

#define BB 256
#define TT 2048
#define HH 128
#define NT 512   // 8 waves

// W[kb+k][c0..c0+3] is contiguous -> float4 load.
#define LOADW(k) \
    float4 w##k = *(const float4*)&W[(kb + (k)) * HH + c0];

#define KEEPW(k) \
    asm volatile("" : "+v"(w##k.x), "+v"(w##k.y), "+v"(w##k.z), "+v"(w##k.w));

// One h value times the 4 owned columns.
#define MACR(k, hv) { \
    a0 = fmaf((hv), w##k.x, a0); \
    a1 = fmaf((hv), w##k.y, a1); \
    a2 = fmaf((hv), w##k.z, a2); \
    a3 = fmaf((hv), w##k.w, a3); }

// DPP row_ror butterfly stage: v += ror_n(v) within the 16-lane row.
// ROW_ROR:n = 0x120+n. After n=8,4,2,1 every row lane holds the row sum.
#define RORADD(v, ctrl) { \
    int _o = __builtin_amdgcn_mov_dpp(__float_as_int(v), (ctrl), 0xf, 0xf, true); \
    (v) += __int_as_float(_o); }

#define ROWSUM(v) RORADD(v, 0x128) RORADD(v, 0x124) RORADD(v, 0x122) RORADD(v, 0x121)

__global__ __launch_bounds__(NT)
__attribute__((amdgpu_waves_per_eu(2, 2)))
void lstm_scan_kernel(
    const float* __restrict__ x,   // [B, T]
    const float* __restrict__ W,   // [H+1, H]
    const float* __restrict__ b,   // [H]
    float* __restrict__ out)       // [B, T, H]
{
    const int tid   = threadIdx.x;
    const int lane  = tid & 63;
    const int wave  = tid >> 6;
    const int s     = lane & 15;                 // K-chunk / row position
    const int m     = lane >> 4;                 // col subgroup
    const int q     = s & 3;                     // owned col within subgroup
    const int c0    = (wave << 4) | (m << 2);    // first of 4 cols
    const int csel  = c0 + q;                    // owned col (state, x-term)
    const int kb    = s << 3;                    // first row of K-chunk
    const int batch = blockIdx.x;

    __shared__ float xs[TT];          // 8 KB : this batch row's x
    __shared__ float hb[2][16 * 12];  // 1.5 KB: dbuf; h group s at float 12s
                                      // (8 used + 4 pad -> 2-way banks, free)

    for (int t = tid; t < TT; t += NT) {
        xs[t] = x[(size_t)batch * TT + t];
    }
    if (tid < 2 * 16 * 12) ((float*)hb)[tid] = 0.0f;   // h(0) = 0

    // W rows [kb, kb+8) x cols [c0, c0+4) -> 8 named float4s (32 VGPRs).
    LOADW(0) LOADW(1) LOADW(2) LOADW(3) LOADW(4) LOADW(5) LOADW(6) LOADW(7)
    KEEPW(0) KEEPW(1) KEEPW(2) KEEPW(3) KEEPW(4) KEEPW(5) KEEPW(6) KEEPW(7)

    const float wxv = W[HH * HH + csel];   // x-weight of owned col
    const float bv  = b[csel];             // bias of owned col

    float c = 0.0f;                        // c[csel], replicated x4
    const bool writer = (s < 4);           // one replica set writes
    float* outp = out + (size_t)batch * TT * HH + csel;

    // h read: group s, 8 floats = 2 x float4 (16B-aligned: 48s bytes).
    const float4* hr0 = (const float4*)&hb[0][12 * s];
    const float4* hr1 = (const float4*)&hb[1][12 * s];
    // h write: owned col csel -> group csel>>3, slot csel&7.
    const int hwidx = 12 * (csel >> 3) + (csel & 7);
    float* hw0 = &hb[0][hwidx];
    float* hw1 = &hb[1][hwidx];

    __syncthreads();   // covers x staging + h init

    for (int t = 0; t < TT; ++t) {
        const float4* hr = (t & 1) ? hr1 : hr0;
        const float4 hA = hr[0];           // h[kb..kb+3]
        const float4 hB = hr[1];           // h[kb+4..kb+7]
        const float xt = xs[t];

        // ---- 32 FMA: 8 rows x 4 owned cols ----
        float a0 = 0.0f, a1 = 0.0f, a2 = 0.0f, a3 = 0.0f;
        MACR(0, hA.x) MACR(1, hA.y) MACR(2, hA.z) MACR(3, hA.w)
        MACR(4, hB.x) MACR(5, hB.y) MACR(6, hB.z) MACR(7, hB.w)

        // ---- K-reduction: 16-lane row butterfly per accumulator ----
        ROWSUM(a0) ROWSUM(a1) ROWSUM(a2) ROWSUM(a3)

        // ---- pick own col's sum (q = s&3), finish g ----
        const float tA   = (q & 1) ? a1 : a0;
        const float tB   = (q & 1) ? a3 : a2;
        const float gsum = (q & 2) ? tB : tA;
        const float g    = fmaf(xt, wxv, gsum + bv);

        const float sg = 1.0f / (1.0f + __expf(-g));
        c = sg * (c + g);
        const float hn = sg * c;           // next step's h[csel]

        if (writer) {
            *((t & 1) ? hw0 : hw1) = hn;   // buffer (t+1)&1, conflict-free
            outp[(size_t)t * HH] = hn;     // fire-and-forget (never drained)
        }

        asm volatile("s_waitcnt lgkmcnt(0)" ::: "memory");
        __builtin_amdgcn_s_barrier();
        asm volatile("" ::: "memory");     // keep next reads below the barrier
    }
}

extern "C" void kernel_launch(void* const* d_in, const int* in_sizes, int n_in,
                              void* d_out, int out_size, void* d_ws, size_t ws_size,
                              hipStream_t stream) {
    const float* x = (const float*)d_in[0];
    const float* W = (const float*)d_in[1];
    const float* b = (const float*)d_in[2];
    float* out = (float*)d_out;

    lstm_scan_kernel<<<BB, NT, 0, stream>>>(x, W, b, out);
}